// Round 2
// baseline (544.447 us; speedup 1.0000x reference)
//
#include <hip/hip_runtime.h>

#define N_HITS 8192
#define E_MAX  8192
#define NSTA   32
#define NCHUNK 128   // N_HITS / 64

typedef float v4f __attribute__((ext_vector_type(4)));

// ---- workspace layout (bytes) ----
#define WS_HITA    0         // float4[8192]  (phin, zn, ev, st)
#define WS_HTRACK  131072    // float [8192]
#define WS_CAND    163840    // float4[8192]  (phin, zn, ev, track) sorted by station
#define WS_CCNT    294912    // int[32*128]
#define WS_COFF    311296    // int[32*128]
#define WS_BSTART  327680    // int[33]
#define WS_RCNT    327840    // int[8192]
#define WS_ROFF    360608    // int[8192]
#define WS_TOTAL   393376    // int[1]
#define WS_RIQ     393472    // float[8192]   dst track value per edge (or -1)
#define WS_ROQ     426240    // float[8192]   src track value per edge (or -1)

// ---- output layout (float elements) ----
#define OFF_X  0
#define OFF_RI 24576
#define OFF_RO 67133440
#define OFF_Y  134242304
#define OFF_E  134250496
#define OFF_M  134266880

// K1: normalize, write X and y_lbl, build per-hit packed data
__global__ void k_pre(const float* __restrict__ ed, float* __restrict__ out,
                      float4* __restrict__ hitA, float* __restrict__ htrack) {
    int h = blockIdx.x * blockDim.x + threadIdx.x;
    if (h >= N_HITS) return;
    const float* row = ed + h * 6;
    float ev = row[0], x = row[1], y = row[2], z = row[3], st = row[4], tr = row[5];
    float r   = sqrtf(x * x + y * y);
    float phi = atan2f(x, y);                       // jnp.arctan2(x, y)
    float rn   = 2.0f * (r   - 269.0f)  / 312.0f  - 1.0f;
    float phin = 2.0f * (phi + 3.15f)   / 6.3f    - 1.0f;
    float zn   = 2.0f * (z   + 2386.0f) / 4772.0f - 1.0f;
    out[OFF_X + h * 3 + 0] = rn;
    out[OFF_X + h * 3 + 1] = phin;
    out[OFF_X + h * 3 + 2] = zn;
    out[OFF_Y + h] = 0.0f;
    hitA[h] = make_float4(phin, zn, (float)(int)ev, (float)(int)st);
    htrack[h] = tr;
}

// K2: per-64-chunk station histogram (stable counting sort, pass 1)
__global__ void k_hist(const float4* __restrict__ hitA, int* __restrict__ ccnt) {
    int tid = threadIdx.x;
    int lane = tid & 63;
    int w = blockIdx.x * (blockDim.x >> 6) + (tid >> 6);
    int h = w * 64 + lane;
    int st = (int)hitA[h].w;
    for (int b = 0; b < NSTA; ++b) {
        unsigned long long m = __ballot(st == b);
        if (lane == 0) ccnt[b * NCHUNK + w] = __popcll(m);
    }
}

// K3: exclusive scan of 32*128 chunk counts (bucket-major) + bucket starts
__global__ void k_scan_chunks(const int* __restrict__ cnt, int* __restrict__ off,
                              int* __restrict__ bstart) {
    __shared__ int sums[256];
    int tid = threadIdx.x;
    int base = tid * 16;
    int loc[16]; int s = 0;
    for (int k = 0; k < 16; ++k) { loc[k] = cnt[base + k]; s += loc[k]; }
    sums[tid] = s; __syncthreads();
    for (int d = 1; d < 256; d <<= 1) {
        int v = (tid >= d) ? sums[tid - d] : 0;
        __syncthreads();
        sums[tid] += v;
        __syncthreads();
    }
    int run = sums[tid] - s;
    for (int k = 0; k < 16; ++k) { off[base + k] = run; run += loc[k]; }
    __syncthreads();
    if (tid < NSTA) bstart[tid] = off[tid * NCHUNK];
    if (tid == 0)   bstart[NSTA] = N_HITS;
}

// K4: stable scatter into station-sorted candidate array
__global__ void k_scatter(const float4* __restrict__ hitA, const float* __restrict__ htrack,
                          const int* __restrict__ coff, float4* __restrict__ cand) {
    int tid = threadIdx.x;
    int lane = tid & 63;
    int w = blockIdx.x * (blockDim.x >> 6) + (tid >> 6);
    int h = w * 64 + lane;
    float4 a = hitA[h];
    float tr = htrack[h];
    int st = (int)a.w;
    for (int b = 0; b < NSTA; ++b) {
        unsigned long long m = __ballot(st == b);
        if (st == b) {
            int rank = __popcll(m & ((1ull << lane) - 1ull));
            cand[coff[b * NCHUNK + w] + rank] = make_float4(a.x, a.y, a.z, tr);
        }
    }
}

__device__ __forceinline__ bool edge_pred(float4 me, float4 cj) {
    float dphi = cj.x - me.x;
    float dz   = cj.y - me.y;
    return (cj.z == me.z) & (dphi > -0.04f) & (dphi < 0.04f)
                          & (dz > -0.03f) & (dz < 0.03f);
}

// K5: per-row edge count (one wave per row, scans target-station bucket)
__global__ void k_rowcount(const float4* __restrict__ hitA, const float4* __restrict__ cand,
                           const int* __restrict__ bstart, int* __restrict__ rcnt) {
    int tid = threadIdx.x;
    int lane = tid & 63;
    int row = blockIdx.x * (blockDim.x >> 6) + (tid >> 6);
    float4 me = hitA[row];
    int b = (int)me.w + 1;
    int cnt = 0;
    if (b >= 1 && b < NSTA) {
        int s = bstart[b], e = bstart[b + 1];
        for (int k0 = s; k0 < e; k0 += 64) {
            int kk = k0 + lane;
            bool p = false;
            if (kk < e) p = edge_pred(me, cand[kk]);
            cnt += __popcll(__ballot(p));
        }
    }
    if (lane == 0) rcnt[row] = cnt;
}

// K6: exclusive scan of 8192 row counts + total
__global__ void k_scan_rows(const int* __restrict__ cnt, int* __restrict__ off,
                            int* __restrict__ total) {
    __shared__ int sums[256];
    int tid = threadIdx.x;
    int base = tid * 32;
    int loc[32]; int s = 0;
    for (int k = 0; k < 32; ++k) { loc[k] = cnt[base + k]; s += loc[k]; }
    sums[tid] = s; __syncthreads();
    for (int d = 1; d < 256; d <<= 1) {
        int v = (tid >= d) ? sums[tid - d] : 0;
        __syncthreads();
        sums[tid] += v;
        __syncthreads();
    }
    int run = sums[tid] - s;
    for (int k = 0; k < 32; ++k) { off[base + k] = run; run += loc[k]; }
    if (tid == 255) *total = sums[255];
}

// K7: ordered edge emission (one wave per row; ballot prefix preserves nonzero order)
__global__ void k_emit(const float4* __restrict__ hitA, const float* __restrict__ htrack,
                       const float4* __restrict__ cand, const int* __restrict__ bstart,
                       const int* __restrict__ roff, float* __restrict__ riq,
                       float* __restrict__ roq, float* __restrict__ out) {
    int tid = threadIdx.x;
    int lane = tid & 63;
    int row = blockIdx.x * (blockDim.x >> 6) + (tid >> 6);
    float4 me = hitA[row];
    int b = (int)me.w + 1;
    if (b < 1 || b >= NSTA) return;   // wave-uniform
    float tr_i = htrack[row];
    int s = bstart[b], e = bstart[b + 1];
    int base = roff[row];
    int c = 0;
    for (int k0 = s; k0 < e; k0 += 64) {
        int kk = k0 + lane;
        float4 cj = make_float4(0.f, 0.f, 0.f, 0.f);
        bool p = false;
        if (kk < e) { cj = cand[kk]; p = edge_pred(me, cj); }
        unsigned long long m = __ballot(p);
        if (p) {
            int idx = base + c + __popcll(m & ((1ull << lane) - 1ull));
            if (idx < E_MAX) {
                riq[idx] = cj.w;                 // dst track  (edges[:,1])
                roq[idx] = tr_i;                 // src track  (edges[:,0])
                out[OFF_E + 2 * idx]     = tr_i;
                out[OFF_E + 2 * idx + 1] = cj.w;
            }
        }
        c += __popcll(m);
    }
}

// K8: edge_mask + pad edges with track[0] (nonzero fill_value=0 -> hit 0)
__global__ void k_pad(const int* __restrict__ total, const float* __restrict__ htrack,
                      float* __restrict__ riq, float* __restrict__ roq,
                      float* __restrict__ out) {
    int e = blockIdx.x * blockDim.x + threadIdx.x;
    if (e >= E_MAX) return;
    int S = *total;
    bool valid = e < S;
    out[OFF_M + e] = valid ? 1.0f : 0.0f;
    if (!valid) {
        float t0 = htrack[0];
        out[OFF_E + 2 * e]     = t0;
        out[OFF_E + 2 * e + 1] = t0;
        riq[e] = -1.0f;   // sentinel: never equals a track value (0..1023)
        roq[e] = -1.0f;
    }
}

// K9: materialize Ri / Ro (the 512 MB write) with float4 non-temporal stores
__global__ void __launch_bounds__(256) k_big(const float* __restrict__ htrack,
                                             const float* __restrict__ riq,
                                             const float* __restrict__ roq,
                                             float* __restrict__ out) {
    int h  = blockIdx.y;
    int e4 = blockIdx.x * 256 + threadIdx.x;   // float4 index in [0, 2048)
    float t = htrack[h];
    const v4f* riq4 = (const v4f*)riq;
    const v4f* roq4 = (const v4f*)roq;
    v4f a = riq4[e4];
    v4f b = roq4[e4];
    v4f ri, ro;
    ri.x = (t == a.x) ? 1.f : 0.f; ri.y = (t == a.y) ? 1.f : 0.f;
    ri.z = (t == a.z) ? 1.f : 0.f; ri.w = (t == a.w) ? 1.f : 0.f;
    ro.x = (t == b.x) ? 1.f : 0.f; ro.y = (t == b.y) ? 1.f : 0.f;
    ro.z = (t == b.z) ? 1.f : 0.f; ro.w = (t == b.w) ? 1.f : 0.f;
    size_t off = (size_t)h * 2048 + e4;
    __builtin_nontemporal_store(ri, (v4f*)(out + OFF_RI) + off);
    __builtin_nontemporal_store(ro, (v4f*)(out + OFF_RO) + off);
}

extern "C" void kernel_launch(void* const* d_in, const int* in_sizes, int n_in,
                              void* d_out, int out_size, void* d_ws, size_t ws_size,
                              hipStream_t stream) {
    const float* ed = (const float*)d_in[0];
    float* out = (float*)d_out;
    char* ws = (char*)d_ws;

    float4* hitA   = (float4*)(ws + WS_HITA);
    float*  htrack = (float*) (ws + WS_HTRACK);
    float4* cand   = (float4*)(ws + WS_CAND);
    int*    ccnt   = (int*)   (ws + WS_CCNT);
    int*    coff   = (int*)   (ws + WS_COFF);
    int*    bstart = (int*)   (ws + WS_BSTART);
    int*    rcnt   = (int*)   (ws + WS_RCNT);
    int*    roffp  = (int*)   (ws + WS_ROFF);
    int*    total  = (int*)   (ws + WS_TOTAL);
    float*  riq    = (float*) (ws + WS_RIQ);
    float*  roq    = (float*) (ws + WS_ROQ);

    hipLaunchKernelGGL(k_pre,        dim3(32),   dim3(256), 0, stream, ed, out, hitA, htrack);
    hipLaunchKernelGGL(k_hist,       dim3(32),   dim3(256), 0, stream, hitA, ccnt);
    hipLaunchKernelGGL(k_scan_chunks,dim3(1),    dim3(256), 0, stream, ccnt, coff, bstart);
    hipLaunchKernelGGL(k_scatter,    dim3(32),   dim3(256), 0, stream, hitA, htrack, coff, cand);
    hipLaunchKernelGGL(k_rowcount,   dim3(2048), dim3(256), 0, stream, hitA, cand, bstart, rcnt);
    hipLaunchKernelGGL(k_scan_rows,  dim3(1),    dim3(256), 0, stream, rcnt, roffp, total);
    hipLaunchKernelGGL(k_emit,       dim3(2048), dim3(256), 0, stream, hitA, htrack, cand, bstart, roffp, riq, roq, out);
    hipLaunchKernelGGL(k_pad,        dim3(32),   dim3(256), 0, stream, total, htrack, riq, roq, out);
    hipLaunchKernelGGL(k_big,        dim3(8, 8192), dim3(256), 0, stream, htrack, riq, roq, out);
}